// Round 6
// baseline (16.454 us; speedup 1.0000x reference)
//
#include <hip/hip_runtime.h>

// DCN cross layer, B x D f32, D = 1024, LAYERS = 3.
// x_{l+1} = x0 * (x_l . w_l) + b_l + x_l
//
// Closed form:
//   d_i = x0 . W_i;  c1 = b0.W1;  c2 = (b0+b1).W2
//   s0 = d0; s1 = (1+s0)d1 + c1; s2 = (1+s0+s1)d2 + c2
//   out = x0*(1+s0+s1+s2) + (b0+b1+b2)
//
// R6: persistent per-wave W/b in registers (loaded once, 64 VGPRs), then a
// 4-row loop software-pipelined 2 deep: row r+1's HBM loads issue before
// row r's compute/reduce/store, so the memory pipe never idles. Stores are
// cached (not NT): the 64 MiB steady-state working set fits L3 across
// graph replays.

#define DDIM 1024
#define RPW 4

typedef float f32x4 __attribute__((ext_vector_type(4)));

__device__ __forceinline__ float dot4(f32x4 a, f32x4 b) {
    return fmaf(a.x, b.x, fmaf(a.y, b.y, fmaf(a.z, b.z, a.w * b.w)));
}

__global__ __launch_bounds__(256) void CrossLayer_kernel(
    const float* __restrict__ x,
    const float* __restrict__ W,
    const float* __restrict__ bias,
    float* __restrict__ out,
    int B)
{
    const int wave = threadIdx.x >> 6;
    const int lane = threadIdx.x & 63;
    const int wid  = blockIdx.x * 4 + wave;
    const int row0 = wid * RPW;
    if (row0 >= B) return;

    const f32x4* w0p = reinterpret_cast<const f32x4*>(W);
    const f32x4* w1p = reinterpret_cast<const f32x4*>(W + DDIM);
    const f32x4* w2p = reinterpret_cast<const f32x4*>(W + 2 * DDIM);
    const f32x4* b0p = reinterpret_cast<const f32x4*>(bias);
    const f32x4* b1p = reinterpret_cast<const f32x4*>(bias + DDIM);
    const f32x4* b2p = reinterpret_cast<const f32x4*>(bias + 2 * DDIM);

    // ---- W/b once per wave, held in registers ----
    f32x4 wv[3][4], bsum[4];
    float c1 = 0.f, c2 = 0.f;
#pragma unroll
    for (int c = 0; c < 4; ++c) {
        const int idx = c * 64 + lane;
        wv[0][c] = w0p[idx];
        wv[1][c] = w1p[idx];
        wv[2][c] = w2p[idx];
        f32x4 bv0 = b0p[idx], bv1 = b1p[idx], bv2 = b2p[idx];
        bsum[c] = bv0 + bv1 + bv2;
        c1 += dot4(bv0, wv[1][c]);
        f32x4 b01 = bv0 + bv1;
        c2 += dot4(b01, wv[2][c]);
    }

    // ---- 4-row loop, 2-deep software pipeline ----
    f32x4 xbuf[2][4];

    // prologue: load row 0
    {
        const f32x4* xr = reinterpret_cast<const f32x4*>(x + (size_t)row0 * DDIM);
#pragma unroll
        for (int c = 0; c < 4; ++c)
            xbuf[0][c] = xr[c * 64 + lane];
    }

#pragma unroll
    for (int r = 0; r < RPW; ++r) {
        const int cur = r & 1, nxt = cur ^ 1;

        // issue next row's loads before touching this row's data
        if (r + 1 < RPW) {
            const f32x4* xr = reinterpret_cast<const f32x4*>(
                x + (size_t)(row0 + r + 1) * DDIM);
#pragma unroll
            for (int c = 0; c < 4; ++c)
                xbuf[nxt][c] = xr[c * 64 + lane];
        }

        // dots against register-resident W
        float d0 = 0.f, d1 = 0.f, d2 = 0.f;
#pragma unroll
        for (int c = 0; c < 4; ++c) {
            d0 += dot4(xbuf[cur][c], wv[0][c]);
            d1 += dot4(xbuf[cur][c], wv[1][c]);
            d2 += dot4(xbuf[cur][c], wv[2][c]);
        }

        // butterfly; fold c1/c2 reduction into row 0's round
#pragma unroll
        for (int off = 32; off > 0; off >>= 1) {
            d0 += __shfl_xor(d0, off, 64);
            d1 += __shfl_xor(d1, off, 64);
            d2 += __shfl_xor(d2, off, 64);
            if (r == 0) {
                c1 += __shfl_xor(c1, off, 64);
                c2 += __shfl_xor(c2, off, 64);
            }
        }

        const float t1 = 1.f + d0;
        const float s1 = fmaf(t1, d1, c1);
        const float t2 = t1 + s1;
        const float s2 = fmaf(t2, d2, c2);
        const float alpha = t2 + s2;

        // cached stores (L3 write-back absorbs the stream across replays)
        f32x4* orow = reinterpret_cast<f32x4*>(out + (size_t)(row0 + r) * DDIM);
#pragma unroll
        for (int c = 0; c < 4; ++c) {
            f32x4 o;
            o.x = fmaf(xbuf[cur][c].x, alpha, bsum[c].x);
            o.y = fmaf(xbuf[cur][c].y, alpha, bsum[c].y);
            o.z = fmaf(xbuf[cur][c].z, alpha, bsum[c].z);
            o.w = fmaf(xbuf[cur][c].w, alpha, bsum[c].w);
            orow[c * 64 + lane] = o;
        }
    }
}

extern "C" void kernel_launch(void* const* d_in, const int* in_sizes, int n_in,
                              void* d_out, int out_size, void* d_ws, size_t ws_size,
                              hipStream_t stream) {
    const float* x  = (const float*)d_in[0];
    const float* W  = (const float*)d_in[1];
    const float* b  = (const float*)d_in[2];
    float* out      = (float*)d_out;

    const int B = in_sizes[0] / DDIM;              // 8192
    const int rows_per_block = 4 * RPW;            // 16
    dim3 grid((B + rows_per_block - 1) / rows_per_block), block(256);
    hipLaunchKernelGGL(CrossLayer_kernel, grid, block, 0, stream,
                       x, W, b, out, B);
}